// Round 7
// baseline (355.119 us; speedup 1.0000x reference)
//
#include <hip/hip_runtime.h>

#define DEV static __device__ __forceinline__

typedef unsigned short u16;
typedef __attribute__((ext_vector_type(8))) __bf16 bf16x8;
typedef __attribute__((ext_vector_type(4))) float f32x4;

DEV float bf2f(u16 u) { union { unsigned int i; float f; } v; v.i = ((unsigned int)u) << 16; return v.f; }
DEV u16 f2bf(float f) {
  union { float f; unsigned int i; } v; v.f = f;
  unsigned int r = v.i + 0x7fffu + ((v.i >> 16) & 1u);
  return (u16)(r >> 16);
}

DEV float gelu_f(float x) {
  float u = 0.7978845608028654f * (x + 0.044715f * x * x * x);
  float e = __expf(2.f * u);
  float t = 1.f - 2.f / (e + 1.f);   // tanh(u), overflow-safe
  return 0.5f * x * (1.f + t);
}

// async global->LDS, 16B per lane; LDS dest = wave-uniform base + lane*16B.
DEV void async16(const u16* g, u16* l) {
  __builtin_amdgcn_global_load_lds(
      (const __attribute__((address_space(1))) unsigned int*)g,
      (__attribute__((address_space(3))) unsigned int*)l, 16, 0, 0);
}

// All six weight repacks in one launch. 32x32 tiles; block id selects segment.
// out[c*R + r] = bf16(in[r*C + c]).
__global__ __launch_bounds__(256) void transpose_all(
    const float* __restrict__ w_q, const float* __restrict__ w_k,
    const float* __restrict__ w_v, const float* __restrict__ w_o,
    const float* __restrict__ w_in, const float* __restrict__ w_out,
    u16* __restrict__ WQKVT, u16* __restrict__ WOT,
    u16* __restrict__ WINT, u16* __restrict__ WOUTT)
{
  int t = blockIdx.x;
  const float* src; u16* dst; int R, C, c0, r0;
  if (t < 3072) {                       // w_q / w_k / w_v: per-head [1024][64]
    int seg = t >> 10, tt = t & 1023;
    int z = tt >> 6, rem = tt & 63;
    const float* w = seg == 0 ? w_q : (seg == 1 ? w_k : w_v);
    src = w + z * 65536;
    dst = WQKVT + seg * 1048576 + z * 65536;
    R = 1024; C = 64;
    c0 = (rem >> 5) * 32; r0 = (rem & 31) * 32;
  } else if (t < 4096) {                // w_o [1024][1024]
    int tt = t - 3072;
    src = w_o; dst = WOT; R = 1024; C = 1024;
    c0 = (tt & 31) * 32; r0 = (tt >> 5) * 32;
  } else if (t < 8192) {                // w_in [1024][4096]
    int tt = t - 4096;
    src = w_in; dst = WINT; R = 1024; C = 4096;
    c0 = (tt & 127) * 32; r0 = (tt >> 7) * 32;
  } else {                              // w_out [4096][1024]
    int tt = t - 8192;
    src = w_out; dst = WOUTT; R = 4096; C = 1024;
    c0 = (tt & 31) * 32; r0 = (tt >> 5) * 32;
  }
  __shared__ float tile[32][33];
  int tx = threadIdx.x & 31, ty = threadIdx.x >> 5;
#pragma unroll
  for (int i = 0; i < 32; i += 8)
    tile[ty + i][tx] = src[(size_t)(r0 + ty + i) * C + (c0 + tx)];
  __syncthreads();
#pragma unroll
  for (int i = 0; i < 32; i += 8)
    dst[(size_t)(c0 + ty + i) * R + (r0 + tx)] = f2bf(tile[tx][ty + i]);
}

// LayerNorm over rows of 1024 fp32 -> bf16 out. One block (256 thr) per row.
__global__ __launch_bounds__(256) void ln_kernel(
    const float* __restrict__ x, const float* __restrict__ g,
    const float* __restrict__ b, u16* __restrict__ out)
{
  int row = blockIdx.x, tid = threadIdx.x;
  const float4 v = ((const float4*)(x + (size_t)row * 1024))[tid];
  float s = v.x + v.y + v.z + v.w;
  float ss = v.x * v.x + v.y * v.y + v.z * v.z + v.w * v.w;
#pragma unroll
  for (int m = 1; m < 64; m <<= 1) { s += __shfl_xor(s, m, 64); ss += __shfl_xor(ss, m, 64); }
  __shared__ float red[8];
  if ((tid & 63) == 0) { red[tid >> 6] = s; red[4 + (tid >> 6)] = ss; }
  __syncthreads();
  s = red[0] + red[1] + red[2] + red[3];
  ss = red[4] + red[5] + red[6] + red[7];
  float mean = s * (1.f / 1024.f);
  float var = ss * (1.f / 1024.f) - mean * mean;
  float rstd = rsqrtf(var + 1e-5f);
  float4 gv = ((const float4*)g)[tid];
  float4 bv = ((const float4*)b)[tid];
  u16* o = out + (size_t)row * 1024 + tid * 4;
  o[0] = f2bf((v.x - mean) * rstd * gv.x + bv.x);
  o[1] = f2bf((v.y - mean) * rstd * gv.y + bv.y);
  o[2] = f2bf((v.z - mean) * rstd * gv.z + bv.z);
  o[3] = f2bf((v.w - mean) * rstd * gv.w + bv.w);
}

// C[M,N] = A[M,K] (bf16 row-major) @ Bt[N,K]^T. Block tile BM x BN, BK=64,
// 4 waves (2x2), wave tile (BM/2) x (BN/2). SINGLE-BUFFERED 2-barrier k-loop
// (R2/R6 structure, best measured): latency hiding comes from cross-block
// occupancy, not in-block pipelining. R3/R4/R5 pipelined variants (dbuf,
// counted vmcnt, 8-phase 256-tile) all measured WORSE at these shapes.
// XCD CHUNK SWIZZLE (T1, FETCH-confirmed 143->57 MB on EPI=3).
// SPLIT-K (gridDim.z): each z-slice covers K/gridDim.z; EPI=3 accumulates
// with native fp32 atomics onto an output pre-initialized by EPI=1
// (out = R2 + b_out), doubling blocks/CU on the grid-capped MLP-out GEMM.
// global_load_lds width=16 staging, 8-chunk xor swizzle on the SOURCE address
// (LDS stays lane-linear; ds_read applies the same xor -> conflict-free).
// EPI: 0 = QKV scatter (Q pre-scaled 1/8, V transposed),
//      1 = +resid -> R2 (fp32) AND out-init = R2 + bias,
//      2 = bias+gelu -> bf16, 3 = split-K atomic accumulate -> fp32
template <int EPI, int BM, int BN>
__global__ __launch_bounds__(256) void gemm_bf16(
    const u16* __restrict__ A, const u16* __restrict__ Bt, int K, int N,
    const float* __restrict__ addv, const float* __restrict__ bias,
    float* __restrict__ outF, float* __restrict__ outF2,
    u16* __restrict__ o0, u16* __restrict__ o1, u16* __restrict__ o2)
{
  constexpr int IM = BM / 32, IN = BN / 32;
  __shared__ u16 lA[BM * 64];
  __shared__ u16 lB[BN * 64];
  const int tid = threadIdx.x;
  const int lane = tid & 63, wave = tid >> 6;
  const int wm = wave >> 1, wn = wave & 1;
  const int quad = lane >> 4, l16 = lane & 15;

  // bijective XCD chunk swizzle over the xy-grid (multiple of 8 everywhere);
  // z-twins share dispatch id mod 8 (z stride = 512 here) -> same XCD.
  const int nwg = gridDim.x * gridDim.y;
  int flat = blockIdx.x + gridDim.x * blockIdx.y;
  flat = (flat & 7) * (nwg >> 3) + (flat >> 3);
  const int bx = flat % gridDim.x;
  const int by = flat / gridDim.x;
  const int m0 = by * BM, n0 = bx * BN;

  f32x4 acc[IM][IN] = {};

  // staging: 8 rows x 8 chunks per wave-instruction, source chunk xor-swizzled
  const int srow = lane >> 3;
  const int soff = ((lane & 7) ^ srow) << 3;

  const int kseg = K / gridDim.z;                 // split-K slice (z=1 -> K)
  const int kbeg = blockIdx.z * kseg, kfin = kbeg + kseg;

  for (int kt = kbeg; kt < kfin; kt += 64) {
    __syncthreads();
#pragma unroll
    for (int q = 0; q < BM / 32; ++q) {
      int rbase = wave * (BM / 4) + q * 8;
      async16(A + (size_t)(m0 + rbase + srow) * K + kt + soff, lA + rbase * 64);
    }
#pragma unroll
    for (int q = 0; q < BN / 32; ++q) {
      int rbase = wave * (BN / 4) + q * 8;
      async16(Bt + (size_t)(n0 + rbase + srow) * K + kt + soff, lB + rbase * 64);
    }
    __syncthreads();
#pragma unroll
    for (int kk = 0; kk < 2; ++kk) {
      bf16x8 af[IM], bfr[IN];
#pragma unroll
      for (int i = 0; i < IM; ++i) {
        int ar = wm * (BM / 2) + i * 16 + l16;
        af[i] = *(const bf16x8*)&lA[ar * 64 + ((((kk * 4) + quad) ^ (ar & 7)) << 3)];
      }
#pragma unroll
      for (int j = 0; j < IN; ++j) {
        int br = wn * (BN / 2) + j * 16 + l16;
        bfr[j] = *(const bf16x8*)&lB[br * 64 + ((((kk * 4) + quad) ^ (br & 7)) << 3)];
      }
#pragma unroll
      for (int i = 0; i < IM; ++i)
#pragma unroll
        for (int j = 0; j < IN; ++j)
          acc[i][j] = __builtin_amdgcn_mfma_f32_16x16x32_bf16(af[i], bfr[j], acc[i][j], 0, 0, 0);
    }
  }

#pragma unroll
  for (int i = 0; i < IM; ++i) {
    const int rowb = m0 + wm * (BM / 2) + i * 16 + quad * 4;
#pragma unroll
    for (int j = 0; j < IN; ++j) {
      const int col = n0 + wn * (BN / 2) + j * 16 + l16;
#pragma unroll
      for (int rr = 0; rr < 4; ++rr) {
        const int m = rowb + rr;
        const float v = acc[i][j][rr];
        if (EPI == 0) {
          int bb = m >> 11, s = m & 2047;
          int proj = col >> 10, hc = col & 1023, hh = hc >> 6, e = hc & 63;
          size_t bhh = (size_t)(bb * 16 + hh);
          if (proj == 0) o0[(bhh * 2048 + s) * 64 + e] = f2bf(v * 0.125f);
          else if (proj == 1) o1[(bhh * 2048 + s) * 64 + e] = f2bf(v);
          else o2[bhh * 131072 + (size_t)e * 2048 + s] = f2bf(v);   // V^T
        } else if (EPI == 1) {
          size_t idx = (size_t)m * N + col;
          float r = v + addv[idx];
          outF[idx] = r;                       // R2 (ln2 input)
          outF2[idx] = r + bias[col];          // out-init for EPI=3 atomics
        } else if (EPI == 2) {
          o0[(size_t)m * N + col] = f2bf(gelu_f(v + bias[col]));
        } else {
          size_t idx = (size_t)m * N + col;
          unsafeAtomicAdd(&outF[idx], v);      // native global_atomic_add_f32
        }
      }
    }
  }
}

// Flash attention, no-max softmax (Q pre-scaled by 1/8; |s| small, exp safe).
// Block = 64 Q rows (4 waves x 16 rows), K-tiles of 64 keys.
// UNIFORM WORK: each block processes a PAIR of q-tiles (31-p and p), exactly
// 33 k-tile-steps per block -> 512 blocks, 2/CU, no load-imbalance tail.
// DOUBLE-BUFFERED K/V staging: stage tile t+1 right after the single barrier,
// compute tile t from the other buffer; the vmcnt(0) drain at the NEXT barrier
// lands after ~800 cycles of compute, hiding the global fetch latency.
// XCD swizzle: 4 (b,h) pairs per XCD (K+V = 2 MB, fits per-XCD L2).
__global__ __launch_bounds__(256) void attn_flash(
    const u16* __restrict__ Q, const u16* __restrict__ K,
    const u16* __restrict__ Vt, u16* __restrict__ Z)
{
  __shared__ u16 lK[2][64 * 64];    // [key][dh], chunks xor-swizzled
  __shared__ u16 lV[2][64 * 64];    // [dh][key], chunks xor-swizzled
  __shared__ u16 lP[4][16 * 64];    // per-wave [row][key], swizzled

  const int tid = threadIdx.x;
  const int lane = tid & 63, wave = tid >> 6;
  const int quad = lane >> 4, l16 = lane & 15;

  const int flat = blockIdx.x;                // 0..511
  const int xcd = flat & 7, w = flat >> 3;    // w in 0..63
  const int bhid = xcd * 4 + (w >> 4);        // 4 (b,h) pairs per XCD
  const int p = w & 15;                       // pair index 0..15
  const int b = bhid >> 4, h = bhid & 15;
  const size_t bh = (size_t)bhid;

  const int nA = 32 - p;                      // k-tiles of segment A (qtile 31-p)
  const int q0A = (31 - p) * 64;
  const int q0B = p * 64;                     // segment B (qtile p): p+1 k-tiles

  const int srow = lane >> 3;
  const int soff = ((lane & 7) ^ srow) << 3;

  u16* myP = lP[wave];

  // stage step s (0..32) into buffer buf
  auto stage = [&](int buf, int s) {
    int kt0 = (s < nA ? s : s - nA) * 64;
#pragma unroll
    for (int q = 0; q < 2; ++q) {
      int rbase = wave * 16 + q * 8;
      async16(K + (bh * 2048 + (size_t)(kt0 + rbase + srow)) * 64 + soff,
              lK[buf] + rbase * 64);
      async16(Vt + bh * 131072 + (size_t)(rbase + srow) * 2048 + kt0 + soff,
              lV[buf] + rbase * 64);
    }
  };

  stage(0, 0);   // prologue; drained by the first barrier

  f32x4 oacc[4] = {};
  float lrow[4] = {};
  int q0w = q0A + wave * 16;

  bf16x8 qf[2];
#pragma unroll
  for (int d = 0; d < 2; ++d)
    qf[d] = *(const bf16x8*)(Q + (bh * 2048 + (size_t)(q0w + l16)) * 64 + d * 32 + quad * 8);

  // one-time row-sum reduce (16 lanes) + normalized write of current segment
  auto writeO = [&]() {
#pragma unroll
    for (int rr = 0; rr < 4; ++rr) {
      float l = lrow[rr];
#pragma unroll
      for (int msk = 1; msk < 16; msk <<= 1) l += __shfl_xor(l, msk, 64);
      lrow[rr] = 1.f / l;
    }
#pragma unroll
    for (int d = 0; d < 4; ++d)
#pragma unroll
      for (int rr = 0; rr < 4; ++rr) {
        int srowq = q0w + quad * 4 + rr;
        Z[((size_t)(b * 2048 + srowq)) * 1024 + h * 64 + d * 16 + l16] =
            f2bf(oacc[d][rr] * lrow[rr]);
      }
  };

  for (int s = 0; s < 33; ++s) {
    if (s == nA) {               // segment A done: flush, switch to segment B
      writeO();
#pragma unroll
      for (int d = 0; d < 4; ++d)
#pragma unroll
        for (int e = 0; e < 4; ++e) oacc[d][e] = 0.f;
#pragma unroll
      for (int rr = 0; rr < 4; ++rr) lrow[rr] = 0.f;
      q0w = q0B + wave * 16;
#pragma unroll
      for (int d = 0; d < 2; ++d)
        qf[d] = *(const bf16x8*)(Q + (bh * 2048 + (size_t)(q0w + l16)) * 64 + d * 32 + quad * 8);
    }

    __syncthreads();             // buf[s&1] staged; buf[s&1^1] readers done
    if (s < 32) stage((s + 1) & 1, s + 1);

    const u16* cK = lK[s & 1];
    const u16* cV = lV[s & 1];
    const int kt0 = (s < nA ? s : s - nA) * 64;

    // ---- S = Q K^T (pre-scaled) ----
    bf16x8 kf[4][2];
#pragma unroll
    for (int j = 0; j < 4; ++j)
#pragma unroll
      for (int d = 0; d < 2; ++d) {
        int key = j * 16 + l16;
        kf[j][d] = *(const bf16x8*)(cK + key * 64 + (((d * 4 + quad) ^ (key & 7)) << 3));
      }
    f32x4 sv[4];
#pragma unroll
    for (int j = 0; j < 4; ++j) {
      f32x4 z = {};
      z = __builtin_amdgcn_mfma_f32_16x16x32_bf16(qf[0], kf[j][0], z, 0, 0, 0);
      z = __builtin_amdgcn_mfma_f32_16x16x32_bf16(qf[1], kf[j][1], z, 0, 0, 0);
      sv[j] = z;
    }

    const bool needMask = (kt0 + 63 > q0w);
    // ---- exp + accumulate row sums (no cross-lane ops) ----
#pragma unroll
    for (int rr = 0; rr < 4; ++rr) {
      int rowl = quad * 4 + rr;
      int rowg = q0w + rowl;
      u16* prow = myP + rowl * 64;
      float accl = lrow[rr];
#pragma unroll
      for (int j = 0; j < 4; ++j) {
        float pv = __expf(sv[j][rr]);
        if (needMask && (kt0 + j * 16 + l16 > rowg)) pv = 0.f;
        accl += pv;
        int chk = j * 2 + (l16 >> 3);
        prow[((chk ^ (rowl & 7)) << 3) + (l16 & 7)] = (u16)(__float_as_uint(pv) >> 16);
      }
      lrow[rr] = accl;
    }

    // ---- O += P V ----
#pragma unroll
    for (int ks = 0; ks < 2; ++ks) {
      int chk = ks * 4 + quad;
      bf16x8 pf, vf[4];
      pf = *(const bf16x8*)(myP + l16 * 64 + ((chk ^ (l16 & 7)) << 3));
#pragma unroll
      for (int d = 0; d < 4; ++d) {
        int dh = d * 16 + l16;
        vf[d] = *(const bf16x8*)(cV + dh * 64 + ((chk ^ (dh & 7)) << 3));
      }
#pragma unroll
      for (int d = 0; d < 4; ++d)
        oacc[d] = __builtin_amdgcn_mfma_f32_16x16x32_bf16(pf, vf[d], oacc[d], 0, 0, 0);
    }
  }

  writeO();                      // segment B flush
}

extern "C" void kernel_launch(void* const* d_in, const int* in_sizes, int n_in,
                              void* d_out, int out_size, void* d_ws, size_t ws_size,
                              hipStream_t stream) {
  const float* resid = (const float*)d_in[0];
  const float* w_q  = (const float*)d_in[1];
  const float* w_k  = (const float*)d_in[2];
  const float* w_v  = (const float*)d_in[3];
  const float* w_o  = (const float*)d_in[4];
  const float* ln1w = (const float*)d_in[5];
  const float* ln1b = (const float*)d_in[6];
  const float* ln2w = (const float*)d_in[7];
  const float* ln2b = (const float*)d_in[8];
  const float* w_in = (const float*)d_in[9];
  const float* b_in = (const float*)d_in[10];
  const float* w_out= (const float*)d_in[11];
  const float* b_out= (const float*)d_in[12];
  float* out = (float*)d_out;

  const size_t MB = 1u << 20;
  char* ws = (char*)d_ws;
  u16* WQKVT = (u16*)(ws + 0);        // [3072][1024] bf16  (6 MB)
  u16* WOT   = (u16*)(ws + 6 * MB);   // [1024][1024]       (2 MB)
  u16* WINT  = (u16*)(ws + 8 * MB);   // [4096][1024]       (8 MB)
  u16* WOUTT = (u16*)(ws + 16 * MB);  // [1024][4096]       (8 MB)
  u16* X1    = (u16*)(ws + 24 * MB);  // ln1 out [4096][1024]
  u16* Qb    = (u16*)(ws + 32 * MB);  // [b,h,s,64], pre-scaled 1/8
  u16* Kb    = (u16*)(ws + 40 * MB);  // [b,h,s,64]
  u16* Vb    = (u16*)(ws + 48 * MB);  // [b,h,64,s]  (transposed)
  u16* Zb    = (u16*)(ws + 56 * MB);  // attn out [4096][1024]
  float* R2  = (float*)(ws + 64 * MB);// resid2 fp32 (16 MB)
  u16* Hb    = (u16*)(ws + 80 * MB);  // ln2 out
  u16* Gb    = (u16*)(ws + 24 * MB);  // gelu out [4096][4096], aliases X1/Q/K/V (dead)

  transpose_all<<<dim3(12288), 256, 0, stream>>>(w_q, w_k, w_v, w_o, w_in, w_out,
                                                 WQKVT, WOT, WINT, WOUTT);
  ln_kernel<<<4096, 256, 0, stream>>>(resid, ln1w, ln1b, X1);
  gemm_bf16<0, 128, 128><<<dim3(24, 32), 256, 0, stream>>>(X1, WQKVT, 1024, 3072, nullptr, nullptr, nullptr, nullptr, Qb, Kb, Vb);
  attn_flash<<<dim3(512), 256, 0, stream>>>(Qb, Kb, Vb, Zb);
  gemm_bf16<1, 128, 64><<<dim3(16, 32), 256, 0, stream>>>(Zb, WOT, 1024, 1024, resid, b_out, R2, out, nullptr, nullptr, nullptr);
  ln_kernel<<<4096, 256, 0, stream>>>(R2, ln2w, ln2b, Hb);
  gemm_bf16<2, 128, 64><<<dim3(64, 32), 256, 0, stream>>>(Hb, WINT, 1024, 4096, nullptr, b_in, nullptr, nullptr, Gb, nullptr, nullptr);
  gemm_bf16<3, 128, 64><<<dim3(16, 32, 2), 256, 0, stream>>>(Gb, WOUTT, 4096, 1024, nullptr, nullptr, out, nullptr, nullptr, nullptr, nullptr);
}

// Round 8
// 333.429 us; speedup vs baseline: 1.0651x; 1.0651x over previous
//
#include <hip/hip_runtime.h>

#define DEV static __device__ __forceinline__

typedef unsigned short u16;
typedef __attribute__((ext_vector_type(8))) __bf16 bf16x8;
typedef __attribute__((ext_vector_type(4))) float f32x4;

DEV float bf2f(u16 u) { union { unsigned int i; float f; } v; v.i = ((unsigned int)u) << 16; return v.f; }
DEV u16 f2bf(float f) {
  union { float f; unsigned int i; } v; v.f = f;
  unsigned int r = v.i + 0x7fffu + ((v.i >> 16) & 1u);
  return (u16)(r >> 16);
}

DEV float gelu_f(float x) {
  float u = 0.7978845608028654f * (x + 0.044715f * x * x * x);
  float e = __expf(2.f * u);
  float t = 1.f - 2.f / (e + 1.f);   // tanh(u), overflow-safe
  return 0.5f * x * (1.f + t);
}

// async global->LDS, 16B per lane; LDS dest = wave-uniform base + lane*16B.
DEV void async16(const u16* g, u16* l) {
  __builtin_amdgcn_global_load_lds(
      (const __attribute__((address_space(1))) unsigned int*)g,
      (__attribute__((address_space(3))) unsigned int*)l, 16, 0, 0);
}

// All six weight repacks in one launch. 32x32 tiles; block id selects segment.
// out[c*R + r] = bf16(in[r*C + c]).
__global__ __launch_bounds__(256) void transpose_all(
    const float* __restrict__ w_q, const float* __restrict__ w_k,
    const float* __restrict__ w_v, const float* __restrict__ w_o,
    const float* __restrict__ w_in, const float* __restrict__ w_out,
    u16* __restrict__ WQKVT, u16* __restrict__ WOT,
    u16* __restrict__ WINT, u16* __restrict__ WOUTT)
{
  int t = blockIdx.x;
  const float* src; u16* dst; int R, C, c0, r0;
  if (t < 3072) {                       // w_q / w_k / w_v: per-head [1024][64]
    int seg = t >> 10, tt = t & 1023;
    int z = tt >> 6, rem = tt & 63;
    const float* w = seg == 0 ? w_q : (seg == 1 ? w_k : w_v);
    src = w + z * 65536;
    dst = WQKVT + seg * 1048576 + z * 65536;
    R = 1024; C = 64;
    c0 = (rem >> 5) * 32; r0 = (rem & 31) * 32;
  } else if (t < 4096) {                // w_o [1024][1024]
    int tt = t - 3072;
    src = w_o; dst = WOT; R = 1024; C = 1024;
    c0 = (tt & 31) * 32; r0 = (tt >> 5) * 32;
  } else if (t < 8192) {                // w_in [1024][4096]
    int tt = t - 4096;
    src = w_in; dst = WINT; R = 1024; C = 4096;
    c0 = (tt & 127) * 32; r0 = (tt >> 7) * 32;
  } else {                              // w_out [4096][1024]
    int tt = t - 8192;
    src = w_out; dst = WOUTT; R = 4096; C = 1024;
    c0 = (tt & 31) * 32; r0 = (tt >> 5) * 32;
  }
  __shared__ float tile[32][33];
  int tx = threadIdx.x & 31, ty = threadIdx.x >> 5;
#pragma unroll
  for (int i = 0; i < 32; i += 8)
    tile[ty + i][tx] = src[(size_t)(r0 + ty + i) * C + (c0 + tx)];
  __syncthreads();
#pragma unroll
  for (int i = 0; i < 32; i += 8)
    dst[(size_t)(c0 + ty + i) * R + (r0 + tx)] = f2bf(tile[tx][ty + i]);
}

// LayerNorm over rows of 1024 fp32 -> bf16 out. One block (256 thr) per row.
__global__ __launch_bounds__(256) void ln_kernel(
    const float* __restrict__ x, const float* __restrict__ g,
    const float* __restrict__ b, u16* __restrict__ out)
{
  int row = blockIdx.x, tid = threadIdx.x;
  const float4 v = ((const float4*)(x + (size_t)row * 1024))[tid];
  float s = v.x + v.y + v.z + v.w;
  float ss = v.x * v.x + v.y * v.y + v.z * v.z + v.w * v.w;
#pragma unroll
  for (int m = 1; m < 64; m <<= 1) { s += __shfl_xor(s, m, 64); ss += __shfl_xor(ss, m, 64); }
  __shared__ float red[8];
  if ((tid & 63) == 0) { red[tid >> 6] = s; red[4 + (tid >> 6)] = ss; }
  __syncthreads();
  s = red[0] + red[1] + red[2] + red[3];
  ss = red[4] + red[5] + red[6] + red[7];
  float mean = s * (1.f / 1024.f);
  float var = ss * (1.f / 1024.f) - mean * mean;
  float rstd = rsqrtf(var + 1e-5f);
  float4 gv = ((const float4*)g)[tid];
  float4 bv = ((const float4*)b)[tid];
  u16* o = out + (size_t)row * 1024 + tid * 4;
  o[0] = f2bf((v.x - mean) * rstd * gv.x + bv.x);
  o[1] = f2bf((v.y - mean) * rstd * gv.y + bv.y);
  o[2] = f2bf((v.z - mean) * rstd * gv.z + bv.z);
  o[3] = f2bf((v.w - mean) * rstd * gv.w + bv.w);
}

// C[M,N] = A[M,K] (bf16 row-major) @ Bt[N,K]^T. Block tile BM x BN, K-step BK,
// 4 waves (2x2), wave tile (BM/2) x (BN/2). SINGLE-BUFFERED 2-barrier k-loop
// (R2/R6 structure, best measured): latency hiding comes from cross-block
// occupancy, not in-block pipelining. R3/R4/R5/R7 variants (dbuf, counted
// vmcnt, 8-phase 256-tile, split-K atomics) all measured null-to-worse.
// BK=128 for the GRID-CAPPED GEMMs (EPI=1/3: 512 blocks = 2 blocks/CU, so the
// 48 KB LDS is free): same bytes staged / LDS reads / MFMAs, HALF the
// barrier+drain events - R7 showed the per-k-step overhead is the
// occupancy-invariant cap. EPI=0/2 keep BK=64 (LDS-binding at 5-6 blocks/CU).
// XCD CHUNK SWIZZLE (T1, FETCH-confirmed 143->57 MB on EPI=3).
// global_load_lds width=16 staging, 16B-chunk xor swizzle on the SOURCE
// address, key = (row&7); ds_read applies the same xor -> conflict-free
// (2-way aliasing only, free per m136).
// EPI: 0 = QKV scatter (Q pre-scaled 1/8, V transposed), 1 = +resid -> fp32,
//      2 = bias+gelu -> bf16, 3 = bias+resid2 -> fp32
template <int EPI, int BM, int BN, int BK>
__global__ __launch_bounds__(256) void gemm_bf16(
    const u16* __restrict__ A, const u16* __restrict__ Bt, int K, int N,
    const float* __restrict__ addv, const float* __restrict__ bias,
    float* __restrict__ outF, u16* __restrict__ o0, u16* __restrict__ o1,
    u16* __restrict__ o2)
{
  constexpr int IM = BM / 32, IN = BN / 32;
  constexpr int RPI = 512 / BK;        // rows per gload_lds instr (8@64, 4@128)
  constexpr int CPR = BK / 8;          // 16B chunks per row
  __shared__ u16 lA[BM * BK];
  __shared__ u16 lB[BN * BK];
  const int tid = threadIdx.x;
  const int lane = tid & 63, wave = tid >> 6;
  const int wm = wave >> 1, wn = wave & 1;
  const int quad = lane >> 4, l16 = lane & 15;

  // bijective XCD chunk swizzle (every grid here is a multiple of 8)
  const int nwg = gridDim.x * gridDim.y;
  int flat = blockIdx.x + gridDim.x * blockIdx.y;
  flat = (flat & 7) * (nwg >> 3) + (flat >> 3);
  const int bx = flat % gridDim.x;
  const int by = flat / gridDim.x;
  const int m0 = by * BM, n0 = bx * BN;

  f32x4 acc[IM][IN] = {};

  // staging: RPI rows x CPR chunks per wave-instruction, chunk xor-swizzled
  const int srow = lane / CPR;
  const int schunk = lane % CPR;

  for (int kt = 0; kt < K; kt += BK) {
    __syncthreads();
#pragma unroll
    for (int q = 0; q < BM / (4 * RPI); ++q) {
      int rbase = wave * (BM / 4) + q * RPI;
      int soff = (schunk ^ ((rbase + srow) & 7)) << 3;
      async16(A + (size_t)(m0 + rbase + srow) * K + kt + soff, lA + rbase * BK);
    }
#pragma unroll
    for (int q = 0; q < BN / (4 * RPI); ++q) {
      int rbase = wave * (BN / 4) + q * RPI;
      int soff = (schunk ^ ((rbase + srow) & 7)) << 3;
      async16(Bt + (size_t)(n0 + rbase + srow) * K + kt + soff, lB + rbase * BK);
    }
    __syncthreads();
#pragma unroll
    for (int kk = 0; kk < BK / 32; ++kk) {
      bf16x8 af[IM], bfr[IN];
#pragma unroll
      for (int i = 0; i < IM; ++i) {
        int ar = wm * (BM / 2) + i * 16 + l16;
        af[i] = *(const bf16x8*)&lA[ar * BK + ((((kk * 4) + quad) ^ (ar & 7)) << 3)];
      }
#pragma unroll
      for (int j = 0; j < IN; ++j) {
        int br = wn * (BN / 2) + j * 16 + l16;
        bfr[j] = *(const bf16x8*)&lB[br * BK + ((((kk * 4) + quad) ^ (br & 7)) << 3)];
      }
#pragma unroll
      for (int i = 0; i < IM; ++i)
#pragma unroll
        for (int j = 0; j < IN; ++j)
          acc[i][j] = __builtin_amdgcn_mfma_f32_16x16x32_bf16(af[i], bfr[j], acc[i][j], 0, 0, 0);
    }
  }

#pragma unroll
  for (int i = 0; i < IM; ++i) {
    const int rowb = m0 + wm * (BM / 2) + i * 16 + quad * 4;
#pragma unroll
    for (int j = 0; j < IN; ++j) {
      const int col = n0 + wn * (BN / 2) + j * 16 + l16;
#pragma unroll
      for (int rr = 0; rr < 4; ++rr) {
        const int m = rowb + rr;
        const float v = acc[i][j][rr];
        if (EPI == 0) {
          int bb = m >> 11, s = m & 2047;
          int proj = col >> 10, hc = col & 1023, hh = hc >> 6, e = hc & 63;
          size_t bhh = (size_t)(bb * 16 + hh);
          if (proj == 0) o0[(bhh * 2048 + s) * 64 + e] = f2bf(v * 0.125f);
          else if (proj == 1) o1[(bhh * 2048 + s) * 64 + e] = f2bf(v);
          else o2[bhh * 131072 + (size_t)e * 2048 + s] = f2bf(v);   // V^T
        } else if (EPI == 1) {
          size_t idx = (size_t)m * N + col;
          outF[idx] = v + addv[idx];
        } else if (EPI == 2) {
          o0[(size_t)m * N + col] = f2bf(gelu_f(v + bias[col]));
        } else {
          size_t idx = (size_t)m * N + col;
          outF[idx] = v + bias[col] + addv[idx];
        }
      }
    }
  }
}

// Flash attention, no-max softmax (Q pre-scaled by 1/8; |s| small, exp safe).
// Block = 64 Q rows (4 waves x 16 rows), K-tiles of 64 keys.
// UNIFORM WORK: each block processes a PAIR of q-tiles (31-p and p), exactly
// 33 k-tile-steps per block -> 512 blocks, 2/CU, no load-imbalance tail.
// DOUBLE-BUFFERED K/V staging: stage tile t+1 right after the single barrier,
// compute tile t from the other buffer; the vmcnt(0) drain at the NEXT barrier
// lands after ~800 cycles of compute, hiding the global fetch latency.
// XCD swizzle: 4 (b,h) pairs per XCD (K+V = 2 MB, fits per-XCD L2).
__global__ __launch_bounds__(256) void attn_flash(
    const u16* __restrict__ Q, const u16* __restrict__ K,
    const u16* __restrict__ Vt, u16* __restrict__ Z)
{
  __shared__ u16 lK[2][64 * 64];    // [key][dh], chunks xor-swizzled
  __shared__ u16 lV[2][64 * 64];    // [dh][key], chunks xor-swizzled
  __shared__ u16 lP[4][16 * 64];    // per-wave [row][key], swizzled

  const int tid = threadIdx.x;
  const int lane = tid & 63, wave = tid >> 6;
  const int quad = lane >> 4, l16 = lane & 15;

  const int flat = blockIdx.x;                // 0..511
  const int xcd = flat & 7, w = flat >> 3;    // w in 0..63
  const int bhid = xcd * 4 + (w >> 4);        // 4 (b,h) pairs per XCD
  const int p = w & 15;                       // pair index 0..15
  const int b = bhid >> 4, h = bhid & 15;
  const size_t bh = (size_t)bhid;

  const int nA = 32 - p;                      // k-tiles of segment A (qtile 31-p)
  const int q0A = (31 - p) * 64;
  const int q0B = p * 64;                     // segment B (qtile p): p+1 k-tiles

  const int srow = lane >> 3;
  const int soff = ((lane & 7) ^ srow) << 3;

  u16* myP = lP[wave];

  // stage step s (0..32) into buffer buf
  auto stage = [&](int buf, int s) {
    int kt0 = (s < nA ? s : s - nA) * 64;
#pragma unroll
    for (int q = 0; q < 2; ++q) {
      int rbase = wave * 16 + q * 8;
      async16(K + (bh * 2048 + (size_t)(kt0 + rbase + srow)) * 64 + soff,
              lK[buf] + rbase * 64);
      async16(Vt + bh * 131072 + (size_t)(rbase + srow) * 2048 + kt0 + soff,
              lV[buf] + rbase * 64);
    }
  };

  stage(0, 0);   // prologue; drained by the first barrier

  f32x4 oacc[4] = {};
  float lrow[4] = {};
  int q0w = q0A + wave * 16;

  bf16x8 qf[2];
#pragma unroll
  for (int d = 0; d < 2; ++d)
    qf[d] = *(const bf16x8*)(Q + (bh * 2048 + (size_t)(q0w + l16)) * 64 + d * 32 + quad * 8);

  // one-time row-sum reduce (16 lanes) + normalized write of current segment
  auto writeO = [&]() {
#pragma unroll
    for (int rr = 0; rr < 4; ++rr) {
      float l = lrow[rr];
#pragma unroll
      for (int msk = 1; msk < 16; msk <<= 1) l += __shfl_xor(l, msk, 64);
      lrow[rr] = 1.f / l;
    }
#pragma unroll
    for (int d = 0; d < 4; ++d)
#pragma unroll
      for (int rr = 0; rr < 4; ++rr) {
        int srowq = q0w + quad * 4 + rr;
        Z[((size_t)(b * 2048 + srowq)) * 1024 + h * 64 + d * 16 + l16] =
            f2bf(oacc[d][rr] * lrow[rr]);
      }
  };

  for (int s = 0; s < 33; ++s) {
    if (s == nA) {               // segment A done: flush, switch to segment B
      writeO();
#pragma unroll
      for (int d = 0; d < 4; ++d)
#pragma unroll
        for (int e = 0; e < 4; ++e) oacc[d][e] = 0.f;
#pragma unroll
      for (int rr = 0; rr < 4; ++rr) lrow[rr] = 0.f;
      q0w = q0B + wave * 16;
#pragma unroll
      for (int d = 0; d < 2; ++d)
        qf[d] = *(const bf16x8*)(Q + (bh * 2048 + (size_t)(q0w + l16)) * 64 + d * 32 + quad * 8);
    }

    __syncthreads();             // buf[s&1] staged; buf[s&1^1] readers done
    if (s < 32) stage((s + 1) & 1, s + 1);

    const u16* cK = lK[s & 1];
    const u16* cV = lV[s & 1];
    const int kt0 = (s < nA ? s : s - nA) * 64;

    // ---- S = Q K^T (pre-scaled) ----
    bf16x8 kf[4][2];
#pragma unroll
    for (int j = 0; j < 4; ++j)
#pragma unroll
      for (int d = 0; d < 2; ++d) {
        int key = j * 16 + l16;
        kf[j][d] = *(const bf16x8*)(cK + key * 64 + (((d * 4 + quad) ^ (key & 7)) << 3));
      }
    f32x4 sv[4];
#pragma unroll
    for (int j = 0; j < 4; ++j) {
      f32x4 z = {};
      z = __builtin_amdgcn_mfma_f32_16x16x32_bf16(qf[0], kf[j][0], z, 0, 0, 0);
      z = __builtin_amdgcn_mfma_f32_16x16x32_bf16(qf[1], kf[j][1], z, 0, 0, 0);
      sv[j] = z;
    }

    const bool needMask = (kt0 + 63 > q0w);
    // ---- exp + accumulate row sums (no cross-lane ops) ----
#pragma unroll
    for (int rr = 0; rr < 4; ++rr) {
      int rowl = quad * 4 + rr;
      int rowg = q0w + rowl;
      u16* prow = myP + rowl * 64;
      float accl = lrow[rr];
#pragma unroll
      for (int j = 0; j < 4; ++j) {
        float pv = __expf(sv[j][rr]);
        if (needMask && (kt0 + j * 16 + l16 > rowg)) pv = 0.f;
        accl += pv;
        int chk = j * 2 + (l16 >> 3);
        prow[((chk ^ (rowl & 7)) << 3) + (l16 & 7)] = (u16)(__float_as_uint(pv) >> 16);
      }
      lrow[rr] = accl;
    }

    // ---- O += P V ----
#pragma unroll
    for (int ks = 0; ks < 2; ++ks) {
      int chk = ks * 4 + quad;
      bf16x8 pf, vf[4];
      pf = *(const bf16x8*)(myP + l16 * 64 + ((chk ^ (l16 & 7)) << 3));
#pragma unroll
      for (int d = 0; d < 4; ++d) {
        int dh = d * 16 + l16;
        vf[d] = *(const bf16x8*)(cV + dh * 64 + ((chk ^ (dh & 7)) << 3));
      }
#pragma unroll
      for (int d = 0; d < 4; ++d)
        oacc[d] = __builtin_amdgcn_mfma_f32_16x16x32_bf16(pf, vf[d], oacc[d], 0, 0, 0);
    }
  }

  writeO();                      // segment B flush
}

extern "C" void kernel_launch(void* const* d_in, const int* in_sizes, int n_in,
                              void* d_out, int out_size, void* d_ws, size_t ws_size,
                              hipStream_t stream) {
  const float* resid = (const float*)d_in[0];
  const float* w_q  = (const float*)d_in[1];
  const float* w_k  = (const float*)d_in[2];
  const float* w_v  = (const float*)d_in[3];
  const float* w_o  = (const float*)d_in[4];
  const float* ln1w = (const float*)d_in[5];
  const float* ln1b = (const float*)d_in[6];
  const float* ln2w = (const float*)d_in[7];
  const float* ln2b = (const float*)d_in[8];
  const float* w_in = (const float*)d_in[9];
  const float* b_in = (const float*)d_in[10];
  const float* w_out= (const float*)d_in[11];
  const float* b_out= (const float*)d_in[12];
  float* out = (float*)d_out;

  const size_t MB = 1u << 20;
  char* ws = (char*)d_ws;
  u16* WQKVT = (u16*)(ws + 0);        // [3072][1024] bf16  (6 MB)
  u16* WOT   = (u16*)(ws + 6 * MB);   // [1024][1024]       (2 MB)
  u16* WINT  = (u16*)(ws + 8 * MB);   // [4096][1024]       (8 MB)
  u16* WOUTT = (u16*)(ws + 16 * MB);  // [1024][4096]       (8 MB)
  u16* X1    = (u16*)(ws + 24 * MB);  // ln1 out [4096][1024]
  u16* Qb    = (u16*)(ws + 32 * MB);  // [b,h,s,64], pre-scaled 1/8
  u16* Kb    = (u16*)(ws + 40 * MB);  // [b,h,s,64]
  u16* Vb    = (u16*)(ws + 48 * MB);  // [b,h,64,s]  (transposed)
  u16* Zb    = (u16*)(ws + 56 * MB);  // attn out [4096][1024]
  float* R2  = (float*)(ws + 64 * MB);// resid2 fp32 (16 MB)
  u16* Hb    = (u16*)(ws + 80 * MB);  // ln2 out
  u16* Gb    = (u16*)(ws + 24 * MB);  // gelu out [4096][4096], aliases X1/Q/K/V (dead)

  transpose_all<<<dim3(12288), 256, 0, stream>>>(w_q, w_k, w_v, w_o, w_in, w_out,
                                                 WQKVT, WOT, WINT, WOUTT);
  ln_kernel<<<4096, 256, 0, stream>>>(resid, ln1w, ln1b, X1);
  gemm_bf16<0, 128, 128, 64><<<dim3(24, 32), 256, 0, stream>>>(X1, WQKVT, 1024, 3072, nullptr, nullptr, nullptr, Qb, Kb, Vb);
  attn_flash<<<dim3(512), 256, 0, stream>>>(Qb, Kb, Vb, Zb);
  gemm_bf16<1, 128, 64, 128><<<dim3(16, 32), 256, 0, stream>>>(Zb, WOT, 1024, 1024, resid, nullptr, R2, nullptr, nullptr, nullptr);
  ln_kernel<<<4096, 256, 0, stream>>>(R2, ln2w, ln2b, Hb);
  gemm_bf16<2, 128, 64, 64><<<dim3(64, 32), 256, 0, stream>>>(Hb, WINT, 1024, 4096, nullptr, b_in, nullptr, Gb, nullptr, nullptr);
  gemm_bf16<3, 128, 64, 128><<<dim3(16, 32), 256, 0, stream>>>(Gb, WOUTT, 4096, 1024, R2, b_out, out, nullptr, nullptr, nullptr);
}